// Round 1
// baseline (1441.990 us; speedup 1.0000x reference)
//
#include <hip/hip_runtime.h>
#include <cfloat>

#define LN_EPS 1e-5f

constexpr int DIM  = 1024;   // input dim
constexpr int CDIM = 256;    // codebook dim
constexpr int K_   = 8192;   // num codes
constexpr int M_   = 8 * 2048; // 16384 rows

// ---------------------------------------------------------------- c_sq
__global__ __launch_bounds__(256) void k_csq(const float* __restrict__ cb,
                                             float* __restrict__ csq) {
    int w    = threadIdx.x >> 6;
    int lane = threadIdx.x & 63;
    int row  = blockIdx.x * 4 + w;
    float4 v = *reinterpret_cast<const float4*>(&cb[(size_t)row * CDIM + lane * 4]);
    float s = v.x * v.x + v.y * v.y + v.z * v.z + v.w * v.w;
#pragma unroll
    for (int m = 1; m < 64; m <<= 1) s += __shfl_xor(s, m, 64);
    if (lane == 0) csq[row] = s;
}

// ------------------------------------------- projection GEMM + fused LN
// tile: 32 rows x 256 cols (full N), 256 threads, 4x8 per thread
__global__ __launch_bounds__(256) void k_proj_ln(const float* __restrict__ x,
                                                 const float* __restrict__ W,
                                                 float* __restrict__ h) {
    __shared__ float xs[32][17];     // [row][k], padded
    __shared__ float wsh[16][256];   // [k][col]
    const int tid = threadIdx.x;
    const int tr  = tid >> 5;        // 0..7 -> rows tr*4..tr*4+3
    const int tc  = tid & 31;        // cols tc*8..tc*8+7
    const int rowblk = blockIdx.x * 32;

    float acc[4][8];
#pragma unroll
    for (int i = 0; i < 4; i++)
#pragma unroll
        for (int j = 0; j < 8; j++) acc[i][j] = 0.f;

    for (int kc = 0; kc < DIM; kc += 16) {
        __syncthreads();
        if (tid < 128) {                       // stage x: 32 rows x 16 k
            int row  = tid >> 2;
            int koff = (tid & 3) * 4;
            float4 v = *reinterpret_cast<const float4*>(
                &x[(size_t)(rowblk + row) * DIM + kc + koff]);
            xs[row][koff + 0] = v.x; xs[row][koff + 1] = v.y;
            xs[row][koff + 2] = v.z; xs[row][koff + 3] = v.w;
        }
        {                                      // stage W: 256 cols x 16 k
            int c0   = tid >> 2;
            int koff = (tid & 3) * 4;
#pragma unroll
            for (int p = 0; p < 4; ++p) {
                int c = c0 + 64 * p;
                float4 v = *reinterpret_cast<const float4*>(
                    &W[(size_t)c * DIM + kc + koff]);
                wsh[koff + 0][c] = v.x; wsh[koff + 1][c] = v.y;
                wsh[koff + 2][c] = v.z; wsh[koff + 3][c] = v.w;
            }
        }
        __syncthreads();
#pragma unroll
        for (int kk = 0; kk < 16; ++kk) {
            float xv[4];
#pragma unroll
            for (int i = 0; i < 4; i++) xv[i] = xs[tr * 4 + i][kk];
            float4 w0 = *reinterpret_cast<const float4*>(&wsh[kk][tc * 8]);
            float4 w1 = *reinterpret_cast<const float4*>(&wsh[kk][tc * 8 + 4]);
            float wv[8] = {w0.x, w0.y, w0.z, w0.w, w1.x, w1.y, w1.z, w1.w};
#pragma unroll
            for (int i = 0; i < 4; i++)
#pragma unroll
                for (int j = 0; j < 8; j++)
                    acc[i][j] = fmaf(xv[i], wv[j], acc[i][j]);
        }
    }

    // fused LayerNorm per row (row owned by 32 consecutive lanes)
#pragma unroll
    for (int i = 0; i < 4; i++) {
        float s = 0.f;
#pragma unroll
        for (int j = 0; j < 8; j++) s += acc[i][j];
#pragma unroll
        for (int m = 1; m < 32; m <<= 1) s += __shfl_xor(s, m, 64);
        float mu = s * (1.0f / 256.0f);
        float sq = 0.f;
#pragma unroll
        for (int j = 0; j < 8; j++) { float d = acc[i][j] - mu; sq = fmaf(d, d, sq); }
#pragma unroll
        for (int m = 1; m < 32; m <<= 1) sq += __shfl_xor(sq, m, 64);
        float var   = sq * (1.0f / 256.0f);
        float scale = 1.0f / sqrtf(var + LN_EPS);
        int row = rowblk + tr * 4 + i;
        float o[8];
#pragma unroll
        for (int j = 0; j < 8; j++) o[j] = (acc[i][j] - mu) * scale;
        float4* dst = reinterpret_cast<float4*>(&h[(size_t)row * CDIM + tc * 8]);
        dst[0] = make_float4(o[0], o[1], o[2], o[3]);
        dst[1] = make_float4(o[4], o[5], o[6], o[7]);
    }
}

// --------------------------------------- dist GEMM + running argmin
// block: 64 rows x 2048-code split; chunks of 64 codes, D in chunks of 64
__global__ __launch_bounds__(256) void k_dist(const float* __restrict__ h,
                                              const float* __restrict__ cb,
                                              const float* __restrict__ csq,
                                              float* __restrict__ candv,
                                              int* __restrict__ candi) {
    __shared__ float ht[64][68];    // [d][row], pad 68 keeps 16B align
    __shared__ float cbt[64][68];   // [d][code]
    __shared__ float csq_l[64];
    const int tid    = threadIdx.x;
    const int rowblk = blockIdx.x * 64;
    const int split  = blockIdx.y;
    const int ks0    = split * (K_ / 4);
    const int r0 = (tid >> 4) * 4;  // 4 rows
    const int c0 = (tid & 15) * 4;  // 4 codes

    float best[4] = {FLT_MAX, FLT_MAX, FLT_MAX, FLT_MAX};
    int   bidx[4] = {0, 0, 0, 0};

    for (int kc = 0; kc < K_ / 4; kc += 64) {
        float acc[4][4] = {};
        for (int dc = 0; dc < CDIM; dc += 64) {
            __syncthreads();
            {
                int rr   = tid >> 4;
                int doff = (tid & 15) * 4;
#pragma unroll
                for (int p = 0; p < 4; p++) {       // h slice 64r x 64d
                    int row = rr + p * 16;
                    float4 v = *reinterpret_cast<const float4*>(
                        &h[(size_t)(rowblk + row) * CDIM + dc + doff]);
                    ht[doff + 0][row] = v.x; ht[doff + 1][row] = v.y;
                    ht[doff + 2][row] = v.z; ht[doff + 3][row] = v.w;
                }
#pragma unroll
                for (int p = 0; p < 4; p++) {       // cb slice 64c x 64d
                    int code = rr + p * 16;
                    float4 v = *reinterpret_cast<const float4*>(
                        &cb[(size_t)(ks0 + kc + code) * CDIM + dc + doff]);
                    cbt[doff + 0][code] = v.x; cbt[doff + 1][code] = v.y;
                    cbt[doff + 2][code] = v.z; cbt[doff + 3][code] = v.w;
                }
            }
            if (dc == 0 && tid < 64) csq_l[tid] = csq[ks0 + kc + tid];
            __syncthreads();
#pragma unroll
            for (int d = 0; d < 64; ++d) {
                float4 hv = *reinterpret_cast<const float4*>(&ht[d][r0]);
                float4 cv = *reinterpret_cast<const float4*>(&cbt[d][c0]);
                float hvv[4] = {hv.x, hv.y, hv.z, hv.w};
                float cvv[4] = {cv.x, cv.y, cv.z, cv.w};
#pragma unroll
                for (int i = 0; i < 4; i++)
#pragma unroll
                    for (int j = 0; j < 4; j++)
                        acc[i][j] = fmaf(hvv[i], cvv[j], acc[i][j]);
            }
        }
        // update running argmin (ascending k, strict < => first-min wins)
#pragma unroll
        for (int j = 0; j < 4; j++) {
            int   kg = ks0 + kc + c0 + j;
            float cs = csq_l[c0 + j];
#pragma unroll
            for (int i = 0; i < 4; i++) {
                float s = fmaf(-2.0f, acc[i][j], cs);
                if (s < best[i]) { best[i] = s; bidx[i] = kg; }
            }
        }
    }
    // reduce (min,argmin) across the 16 lanes sharing each row
#pragma unroll
    for (int i = 0; i < 4; i++) {
        float v = best[i]; int ix = bidx[i];
#pragma unroll
        for (int m = 1; m < 16; m <<= 1) {
            float ov = __shfl_xor(v, m, 64);
            int   oi = __shfl_xor(ix, m, 64);
            if (ov < v || (ov == v && oi < ix)) { v = ov; ix = oi; }
        }
        if ((tid & 15) == 0) {
            int row = rowblk + r0 + i;
            candv[split * M_ + row] = v;
            candi[split * M_ + row] = ix;
        }
    }
}

// ---------------------------------------------------------------- merge
__global__ __launch_bounds__(256) void k_merge(const float* __restrict__ candv,
                                               const int* __restrict__ candi,
                                               int* __restrict__ out) {
    int row = blockIdx.x * 256 + threadIdx.x;
    float bv = FLT_MAX; int bi = 0;
#pragma unroll
    for (int s = 0; s < 4; s++) {
        float v = candv[s * M_ + row];
        int   i = candi[s * M_ + row];
        if (v < bv || (v == bv && i < bi)) { bv = v; bi = i; }
    }
    out[row] = bi;
}

extern "C" void kernel_launch(void* const* d_in, const int* in_sizes, int n_in,
                              void* d_out, int out_size, void* d_ws, size_t ws_size,
                              hipStream_t stream) {
    const float* x  = (const float*)d_in[0];
    const float* W  = (const float*)d_in[1];
    const float* cb = (const float*)d_in[2];

    float* h     = (float*)d_ws;                    // 16384*256 f32
    float* csq   = h + (size_t)M_ * CDIM;           // 8192 f32
    float* candv = csq + K_;                        // 4*16384 f32
    int*   candi = (int*)(candv + 4 * M_);          // 4*16384 i32
    int*   out   = (int*)d_out;

    k_csq   <<<dim3(K_ / 4),      dim3(256), 0, stream>>>(cb, csq);
    k_proj_ln<<<dim3(M_ / 32),    dim3(256), 0, stream>>>(x, W, h);
    k_dist  <<<dim3(M_ / 64, 4),  dim3(256), 0, stream>>>(h, cb, csq, candv, candi);
    k_merge <<<dim3(M_ / 256),    dim3(256), 0, stream>>>(candv, candi, out);
}

// Round 2
// 1060.350 us; speedup vs baseline: 1.3599x; 1.3599x over previous
//
#include <hip/hip_runtime.h>
#include <cfloat>

#define LN_EPS 1e-5f

constexpr int DIM  = 1024;     // input dim
constexpr int CDIM = 256;      // codebook dim
constexpr int K_   = 8192;     // num codes
constexpr int M_   = 16384;    // rows

constexpr int BR   = 128;      // rows per block
constexpr int BC   = 128;      // codes per subtile
constexpr int BK   = 32;       // k chunk
constexpr int NSUB = 8;        // code subtiles per block (1024 codes)

// ---------------------------------------------------------------- c_sq
__global__ __launch_bounds__(256) void k_csq(const float* __restrict__ cb,
                                             float* __restrict__ csq) {
    int w    = threadIdx.x >> 6;
    int lane = threadIdx.x & 63;
    int row  = blockIdx.x * 4 + w;
    float4 v = *reinterpret_cast<const float4*>(&cb[(size_t)row * CDIM + lane * 4]);
    float s = v.x * v.x + v.y * v.y + v.z * v.z + v.w * v.w;
#pragma unroll
    for (int m = 1; m < 64; m <<= 1) s += __shfl_xor(s, m, 64);
    if (lane == 0) csq[row] = s;
}

// ------------------------------------------- projection GEMM + fused LN
__global__ __launch_bounds__(256) void k_proj_ln(const float* __restrict__ x,
                                                 const float* __restrict__ W,
                                                 float* __restrict__ h) {
    __shared__ float xs[32][17];
    __shared__ float wsh[16][256];
    const int tid = threadIdx.x;
    const int tr  = tid >> 5;
    const int tc  = tid & 31;
    const int rowblk = blockIdx.x * 32;

    float acc[4][8];
#pragma unroll
    for (int i = 0; i < 4; i++)
#pragma unroll
        for (int j = 0; j < 8; j++) acc[i][j] = 0.f;

    for (int kc = 0; kc < DIM; kc += 16) {
        __syncthreads();
        if (tid < 128) {
            int row  = tid >> 2;
            int koff = (tid & 3) * 4;
            float4 v = *reinterpret_cast<const float4*>(
                &x[(size_t)(rowblk + row) * DIM + kc + koff]);
            xs[row][koff + 0] = v.x; xs[row][koff + 1] = v.y;
            xs[row][koff + 2] = v.z; xs[row][koff + 3] = v.w;
        }
        {
            int c0   = tid >> 2;
            int koff = (tid & 3) * 4;
#pragma unroll
            for (int p = 0; p < 4; ++p) {
                int c = c0 + 64 * p;
                float4 v = *reinterpret_cast<const float4*>(
                    &W[(size_t)c * DIM + kc + koff]);
                wsh[koff + 0][c] = v.x; wsh[koff + 1][c] = v.y;
                wsh[koff + 2][c] = v.z; wsh[koff + 3][c] = v.w;
            }
        }
        __syncthreads();
#pragma unroll
        for (int kk = 0; kk < 16; ++kk) {
            float xv[4];
#pragma unroll
            for (int i = 0; i < 4; i++) xv[i] = xs[tr * 4 + i][kk];
            float4 w0 = *reinterpret_cast<const float4*>(&wsh[kk][tc * 8]);
            float4 w1 = *reinterpret_cast<const float4*>(&wsh[kk][tc * 8 + 4]);
            float wv[8] = {w0.x, w0.y, w0.z, w0.w, w1.x, w1.y, w1.z, w1.w};
#pragma unroll
            for (int i = 0; i < 4; i++)
#pragma unroll
                for (int j = 0; j < 8; j++)
                    acc[i][j] = fmaf(xv[i], wv[j], acc[i][j]);
        }
    }

#pragma unroll
    for (int i = 0; i < 4; i++) {
        float s = 0.f;
#pragma unroll
        for (int j = 0; j < 8; j++) s += acc[i][j];
#pragma unroll
        for (int m = 1; m < 32; m <<= 1) s += __shfl_xor(s, m, 64);
        float mu = s * (1.0f / 256.0f);
        float sq = 0.f;
#pragma unroll
        for (int j = 0; j < 8; j++) { float d = acc[i][j] - mu; sq = fmaf(d, d, sq); }
#pragma unroll
        for (int m = 1; m < 32; m <<= 1) sq += __shfl_xor(sq, m, 64);
        float var   = sq * (1.0f / 256.0f);
        float scale = 1.0f / sqrtf(var + LN_EPS);
        int row = rowblk + tr * 4 + i;
        float o[8];
#pragma unroll
        for (int j = 0; j < 8; j++) o[j] = (acc[i][j] - mu) * scale;
        float4* dst = reinterpret_cast<float4*>(&h[(size_t)row * CDIM + tc * 8]);
        dst[0] = make_float4(o[0], o[1], o[2], o[3]);
        dst[1] = make_float4(o[4], o[5], o[6], o[7]);
    }
}

// --------------------------------------- dist GEMM + running argmin
// 128 rows x 128 codes per subtile, 8 subtiles/block, 8x8 register tile.
// As/Bs transposed [k][elem]: staging writes are scalar, bank = elem%32
// -> 2-way (free). Inner: A-reads broadcast (free), B-reads 4-way (hidden).
__global__ __launch_bounds__(256, 4) void k_dist(const float* __restrict__ h,
                                                 const float* __restrict__ cb,
                                                 const float* __restrict__ csq,
                                                 unsigned long long* __restrict__ cand) {
    __shared__ float As[BK][BR];
    __shared__ float Bs[BK][BC];
    const int tid    = threadIdx.x;
    const int rowblk = blockIdx.x * BR;
    const int tx  = tid & 15;       // code group: codes tx*8..tx*8+7
    const int ty  = tid >> 4;       // row group:  rows ty*8..ty*8+7
    const int r0  = ty * 8;
    const int c0t = tx * 8;
    const int srow = tid >> 1;      // staging: element (row or code) 0..127
    const int skq  = (tid & 1) * 16;

    for (int cs = 0; cs < NSUB; ++cs) {
        const int cbase = (blockIdx.y * NSUB + cs) * BC;
        float acc[8][8];
#pragma unroll
        for (int i = 0; i < 8; ++i)
#pragma unroll
            for (int j = 0; j < 8; ++j) acc[i][j] = 0.f;

        for (int kc = 0; kc < CDIM; kc += BK) {
            __syncthreads();
            {   // stage h slice: As[k][row]
                const float* src = &h[(size_t)(rowblk + srow) * CDIM + kc + skq];
#pragma unroll
                for (int u = 0; u < 4; ++u) {
                    float4 v = *reinterpret_cast<const float4*>(src + u * 4);
                    int k = skq + u * 4;
                    As[k + 0][srow] = v.x; As[k + 1][srow] = v.y;
                    As[k + 2][srow] = v.z; As[k + 3][srow] = v.w;
                }
            }
            {   // stage cb slice: Bs[k][code]
                const float* src = &cb[(size_t)(cbase + srow) * CDIM + kc + skq];
#pragma unroll
                for (int u = 0; u < 4; ++u) {
                    float4 v = *reinterpret_cast<const float4*>(src + u * 4);
                    int k = skq + u * 4;
                    Bs[k + 0][srow] = v.x; Bs[k + 1][srow] = v.y;
                    Bs[k + 2][srow] = v.z; Bs[k + 3][srow] = v.w;
                }
            }
            __syncthreads();
#pragma unroll 8
            for (int kk = 0; kk < BK; ++kk) {
                float4 a0 = *reinterpret_cast<const float4*>(&As[kk][r0]);
                float4 a1 = *reinterpret_cast<const float4*>(&As[kk][r0 + 4]);
                float4 b0 = *reinterpret_cast<const float4*>(&Bs[kk][c0t]);
                float4 b1 = *reinterpret_cast<const float4*>(&Bs[kk][c0t + 4]);
                float av[8] = {a0.x, a0.y, a0.z, a0.w, a1.x, a1.y, a1.z, a1.w};
                float bv[8] = {b0.x, b0.y, b0.z, b0.w, b1.x, b1.y, b1.z, b1.w};
#pragma unroll
                for (int i = 0; i < 8; ++i)
#pragma unroll
                    for (int j = 0; j < 8; ++j)
                        acc[i][j] = fmaf(av[i], bv[j], acc[i][j]);
            }
        }

        // epilogue: dist = csq - 2*dot, running argmin, u64 atomicMin merge
        float cs_l[8];
#pragma unroll
        for (int j = 0; j < 8; ++j) cs_l[j] = csq[cbase + c0t + j];
#pragma unroll
        for (int i = 0; i < 8; ++i) {
            float bv = FLT_MAX; int bi = 0x7FFFFFFF;
#pragma unroll
            for (int j = 0; j < 8; ++j) {          // j ascending => first-min
                float s = fmaf(-2.0f, acc[i][j], cs_l[j]);
                if (s < bv) { bv = s; bi = cbase + c0t + j; }
            }
#pragma unroll
            for (int m = 1; m < 16; m <<= 1) {     // reduce across 16 code-groups
                float ov = __shfl_xor(bv, m, 64);
                int   oi = __shfl_xor(bi, m, 64);
                if (ov < bv || (ov == bv && oi < bi)) { bv = ov; bi = oi; }
            }
            if (tx == 0) {
                unsigned int b   = __float_as_uint(bv);
                unsigned int key = (b & 0x80000000u) ? ~b : (b | 0x80000000u);
                unsigned long long pk =
                    ((unsigned long long)key << 32) | (unsigned int)bi;
                atomicMin(&cand[rowblk + r0 + i], pk);
            }
        }
    }
}

// ---------------------------------------------------------------- extract
__global__ __launch_bounds__(256) void k_extract(const unsigned long long* __restrict__ cand,
                                                 int* __restrict__ out) {
    int r = blockIdx.x * 256 + threadIdx.x;
    out[r] = (int)(cand[r] & 0xFFFFFFFFull);
}

extern "C" void kernel_launch(void* const* d_in, const int* in_sizes, int n_in,
                              void* d_out, int out_size, void* d_ws, size_t ws_size,
                              hipStream_t stream) {
    const float* x  = (const float*)d_in[0];
    const float* W  = (const float*)d_in[1];
    const float* cb = (const float*)d_in[2];

    float* h   = (float*)d_ws;                       // 16384*256 f32 = 16 MB
    float* csq = h + (size_t)M_ * CDIM;              // 8192 f32
    unsigned long long* cand =
        (unsigned long long*)(csq + K_);             // 16384 u64 = 128 KB
    int* out = (int*)d_out;

    hipMemsetAsync(cand, 0xFF, (size_t)M_ * 8, stream);   // u64 max = min identity
    k_csq    <<<dim3(K_ / 4),   dim3(256), 0, stream>>>(cb, csq);
    k_proj_ln<<<dim3(M_ / 32),  dim3(256), 0, stream>>>(x, W, h);
    k_dist   <<<dim3(M_ / BR, K_ / (BC * NSUB)), dim3(256), 0, stream>>>(h, cb, csq, cand);
    k_extract<<<dim3(M_ / 256), dim3(256), 0, stream>>>(cand, out);
}

// Round 4
// 863.691 us; speedup vs baseline: 1.6696x; 1.2277x over previous
//
#include <hip/hip_runtime.h>
#include <cfloat>

#define LN_EPS 1e-5f

constexpr int DIM  = 1024;
constexpr int CDIM = 256;
constexpr int K_   = 8192;
constexpr int M_   = 16384;

typedef short bf16x8 __attribute__((ext_vector_type(8)));
typedef float f32x4  __attribute__((ext_vector_type(4)));

__device__ inline unsigned short f2bf(float x) {          // RNE bf16
    unsigned u = __float_as_uint(x);
    unsigned r = (u + 0x7fffu + ((u >> 16) & 1u)) >> 16;
    return (unsigned short)r;
}
__device__ inline float bf2f(unsigned short b) {
    return __uint_as_float(((unsigned)b) << 16);
}

// merge top-2 list (v1,i1,v2,i2) with (ov1,oi1,ov2,oi2); order: (v,i) lexicographic
__device__ inline void merge2(float& v1, int& i1, float& v2, int& i2,
                              float ov1, int oi1, float ov2, int oi2) {
    bool oless = (ov1 < v1) || (ov1 == v1 && oi1 < i1);
    if (oless) {
        bool t = (v1 < ov2) || (v1 == ov2 && i1 < oi2);
        v2 = t ? v1 : ov2; i2 = t ? i1 : oi2;
        v1 = ov1; i1 = oi1;
    } else {
        bool t = (ov1 < v2) || (ov1 == v2 && oi1 < i2);
        v2 = t ? ov1 : v2; i2 = t ? oi1 : i2;
    }
}

// ---------------------------------------------------------------- c_sq
__global__ __launch_bounds__(256) void k_csq(const float* __restrict__ cb,
                                             float* __restrict__ csq) {
    int w    = threadIdx.x >> 6;
    int lane = threadIdx.x & 63;
    int row  = blockIdx.x * 4 + w;
    float4 v = *reinterpret_cast<const float4*>(&cb[(size_t)row * CDIM + lane * 4]);
    float s = v.x * v.x + v.y * v.y + v.z * v.z + v.w * v.w;
#pragma unroll
    for (int m = 1; m < 64; m <<= 1) s += __shfl_xor(s, m, 64);
    if (lane == 0) csq[row] = s;
}

// ------------------------- projection GEMM + fused LN + bf16 hi/lo split out
__global__ __launch_bounds__(256) void k_proj_ln(const float* __restrict__ x,
                                                 const float* __restrict__ W,
                                                 float* __restrict__ h,
                                                 unsigned short* __restrict__ Aexp) {
    __shared__ float xs[32][17];
    __shared__ float wsh[16][256];
    const int tid = threadIdx.x;
    const int tr  = tid >> 5;
    const int tc  = tid & 31;
    const int rowblk = blockIdx.x * 32;

    float acc[4][8];
#pragma unroll
    for (int i = 0; i < 4; i++)
#pragma unroll
        for (int j = 0; j < 8; j++) acc[i][j] = 0.f;

    for (int kc = 0; kc < DIM; kc += 16) {
        __syncthreads();
        if (tid < 128) {
            int row  = tid >> 2;
            int koff = (tid & 3) * 4;
            float4 v = *reinterpret_cast<const float4*>(
                &x[(size_t)(rowblk + row) * DIM + kc + koff]);
            xs[row][koff + 0] = v.x; xs[row][koff + 1] = v.y;
            xs[row][koff + 2] = v.z; xs[row][koff + 3] = v.w;
        }
        {
            int c0   = tid >> 2;
            int koff = (tid & 3) * 4;
#pragma unroll
            for (int p = 0; p < 4; ++p) {
                int c = c0 + 64 * p;
                float4 v = *reinterpret_cast<const float4*>(
                    &W[(size_t)c * DIM + kc + koff]);
                wsh[koff + 0][c] = v.x; wsh[koff + 1][c] = v.y;
                wsh[koff + 2][c] = v.z; wsh[koff + 3][c] = v.w;
            }
        }
        __syncthreads();
#pragma unroll
        for (int kk = 0; kk < 16; ++kk) {
            float xv[4];
#pragma unroll
            for (int i = 0; i < 4; i++) xv[i] = xs[tr * 4 + i][kk];
            float4 w0 = *reinterpret_cast<const float4*>(&wsh[kk][tc * 8]);
            float4 w1 = *reinterpret_cast<const float4*>(&wsh[kk][tc * 8 + 4]);
            float wv[8] = {w0.x, w0.y, w0.z, w0.w, w1.x, w1.y, w1.z, w1.w};
#pragma unroll
            for (int i = 0; i < 4; i++)
#pragma unroll
                for (int j = 0; j < 8; j++)
                    acc[i][j] = fmaf(xv[i], wv[j], acc[i][j]);
        }
    }

#pragma unroll
    for (int i = 0; i < 4; i++) {
        float s = 0.f;
#pragma unroll
        for (int j = 0; j < 8; j++) s += acc[i][j];
#pragma unroll
        for (int m = 1; m < 32; m <<= 1) s += __shfl_xor(s, m, 64);
        float mu = s * (1.0f / 256.0f);
        float sq = 0.f;
#pragma unroll
        for (int j = 0; j < 8; j++) { float d = acc[i][j] - mu; sq = fmaf(d, d, sq); }
#pragma unroll
        for (int m = 1; m < 32; m <<= 1) sq += __shfl_xor(sq, m, 64);
        float var   = sq * (1.0f / 256.0f);
        float scale = 1.0f / sqrtf(var + LN_EPS);
        int row = rowblk + tr * 4 + i;
        float o[8];
#pragma unroll
        for (int j = 0; j < 8; j++) o[j] = (acc[i][j] - mu) * scale;
        float4* dst = reinterpret_cast<float4*>(&h[(size_t)row * CDIM + tc * 8]);
        dst[0] = make_float4(o[0], o[1], o[2], o[3]);
        dst[1] = make_float4(o[4], o[5], o[6], o[7]);
        // bf16 hi/lo split, row layout: [hi(256) | lo(256)]
        bf16x8 hi8, lo8;
#pragma unroll
        for (int j = 0; j < 8; j++) {
            unsigned short hu = f2bf(o[j]);
            hi8[j] = (short)hu;
            lo8[j] = (short)f2bf(o[j] - bf2f(hu));
        }
        *reinterpret_cast<bf16x8*>(&Aexp[(size_t)row * 512 + tc * 8])       = hi8;
        *reinterpret_cast<bf16x8*>(&Aexp[(size_t)row * 512 + 256 + tc * 8]) = lo8;
    }
}

// ------------------------------------------- codebook bf16 hi/lo split
__global__ __launch_bounds__(256) void k_expand_cb(const float* __restrict__ cb,
                                                   unsigned short* __restrict__ Bexp) {
    int gid = blockIdx.x * 256 + threadIdx.x;  // 8192*32 threads
    int row = gid >> 5, t = gid & 31;
    const float4* src = reinterpret_cast<const float4*>(&cb[(size_t)row * CDIM + t * 8]);
    float4 v0 = src[0], v1 = src[1];
    float f[8] = {v0.x, v0.y, v0.z, v0.w, v1.x, v1.y, v1.z, v1.w};
    bf16x8 hi8, lo8;
#pragma unroll
    for (int j = 0; j < 8; j++) {
        unsigned short hu = f2bf(f[j]);
        hi8[j] = (short)hu;
        lo8[j] = (short)f2bf(f[j] - bf2f(hu));
    }
    *reinterpret_cast<bf16x8*>(&Bexp[(size_t)row * 512 + t * 8])       = hi8;
    *reinterpret_cast<bf16x8*>(&Bexp[(size_t)row * 512 + 256 + t * 8]) = lo8;
}

// --------------------------------------- bf16-split dist GEMM + top-2 epilogue
// 128 rows x 128 codes tiles, sweep 8 code-subtiles; K_eff = 768 (hi,hi,lo x hi,lo,hi)
__global__ __launch_bounds__(256) void k_dist_mfma(const unsigned short* __restrict__ Aexp,
                                                   const unsigned short* __restrict__ Bexp,
                                                   const float* __restrict__ csq,
                                                   float4* __restrict__ top2ws) {
    __shared__ unsigned short As[128 * 64];   // 16 KB, row stride 128 B
    __shared__ unsigned short Bs[128 * 64];
    __shared__ float rv1[128], rv2[128];
    __shared__ int   ri1[128], ri2[128];
    __shared__ float sv1[2][16], sv2[2][16];
    __shared__ int   si1[2][16], si2[2][16];

    const int tid  = threadIdx.x;
    const int w    = tid >> 6;
    const int lane = tid & 63;
    const int rowblk = blockIdx.x * 128;
    const int colgrp = blockIdx.y;            // 0..7 -> codes colgrp*1024 ...
    const int wr = (w >> 1) * 64;
    const int wc = (w & 1) * 64;

    if (tid < 128) {
        rv1[tid] = FLT_MAX; rv2[tid] = FLT_MAX;
        ri1[tid] = 0x7fffffff; ri2[tid] = 0x7fffffff;
    }

    const int srow  = lane >> 3;              // 0..7 within 8-row group
    const int gslot = (lane & 7) ^ srow;      // pre-swizzled global 16B slot

    for (int cs = 0; cs < 8; ++cs) {
        const int cbase = colgrp * 1024 + cs * 128;
        f32x4 acc[4][4];
#pragma unroll
        for (int i = 0; i < 4; i++)
#pragma unroll
            for (int j = 0; j < 4; j++) acc[i][j] = (f32x4){0.f, 0.f, 0.f, 0.f};

        for (int c = 0; c < 12; ++c) {
            // byte offset within a 1024-B (hi|lo) row for this 64-k' chunk
            int moffA = ((c >= 8) ? 512 : 0) + (c & 3) * 128;          // hi,hi,lo
            int moffB = ((c >= 4 && c < 8) ? 512 : 0) + (c & 3) * 128; // hi,lo,hi
            __syncthreads();
#pragma unroll
            for (int sub = 0; sub < 4; ++sub) {
                int rloc = w * 32 + sub * 8;                  // wave-uniform
                {
                    const char* ag = (const char*)Aexp +
                        (size_t)(rowblk + rloc + srow) * 1024 + moffA + gslot * 16;
                    unsigned short* adst = As + rloc * 64;
                    __builtin_amdgcn_global_load_lds(
                        (const __attribute__((address_space(1))) unsigned int*)ag,
                        (__attribute__((address_space(3))) unsigned int*)adst, 16, 0, 0);
                }
                {
                    const char* bg = (const char*)Bexp +
                        (size_t)(cbase + rloc + srow) * 1024 + moffB + gslot * 16;
                    unsigned short* bdst = Bs + rloc * 64;
                    __builtin_amdgcn_global_load_lds(
                        (const __attribute__((address_space(1))) unsigned int*)bg,
                        (__attribute__((address_space(3))) unsigned int*)bdst, 16, 0, 0);
                }
            }
            __syncthreads();
#pragma unroll
            for (int ks = 0; ks < 2; ++ks) {
                bf16x8 af[4], bfr[4];
#pragma unroll
                for (int f = 0; f < 4; ++f) {
                    int row  = wr + f * 16 + (lane & 15);
                    int slot = (ks * 4 + (lane >> 4)) ^ (row & 7);
                    af[f] = *reinterpret_cast<const bf16x8*>(
                        (const char*)As + row * 128 + slot * 16);
                    int col   = wc + f * 16 + (lane & 15);
                    int cslot = (ks * 4 + (lane >> 4)) ^ (col & 7);
                    bfr[f] = *reinterpret_cast<const bf16x8*>(
                        (const char*)Bs + col * 128 + cslot * 16);
                }
#pragma unroll
                for (int fi = 0; fi < 4; fi++)
#pragma unroll
                    for (int fj = 0; fj < 4; fj++)
                        acc[fi][fj] = __builtin_amdgcn_mfma_f32_16x16x32_bf16(
                            af[fi], bfr[fj], acc[fi][fj], 0, 0, 0);
            }
        }

        // ---- epilogue: per-row top-2 over this 128-code subtile
        float c4[4]; int cIdx[4];
#pragma unroll
        for (int fj = 0; fj < 4; fj++) {
            int col = cbase + wc + fj * 16 + (lane & 15);
            c4[fj] = csq[col]; cIdx[fj] = col;
        }
#pragma unroll
        for (int fi = 0; fi < 4; ++fi) {
            float v1a[4], v2a[4]; int i1a[4], i2a[4];
#pragma unroll
            for (int reg = 0; reg < 4; ++reg) {
                float v1 = FLT_MAX, v2 = FLT_MAX; int i1 = 0x7fffffff, i2 = 0x7fffffff;
#pragma unroll
                for (int fj = 0; fj < 4; ++fj) {
                    float s = fmaf(-2.0f, acc[fi][fj][reg], c4[fj]);
                    int ci = cIdx[fj];
                    if (s < v1 || (s == v1 && ci < i1)) { v2 = v1; i2 = i1; v1 = s; i1 = ci; }
                    else if (s < v2 || (s == v2 && ci < i2)) { v2 = s; i2 = ci; }
                }
#pragma unroll
                for (int m = 1; m < 16; m <<= 1) {
                    float ov1 = __shfl_xor(v1, m, 64), ov2 = __shfl_xor(v2, m, 64);
                    int   oi1 = __shfl_xor(i1, m, 64), oi2 = __shfl_xor(i2, m, 64);
                    merge2(v1, i1, v2, i2, ov1, oi1, ov2, oi2);
                }
                v1a[reg] = v1; v2a[reg] = v2; i1a[reg] = i1; i2a[reg] = i2;
            }
            __syncthreads();
            if ((w & 1) == 1 && (lane & 15) == 0) {
                int half = w >> 1, sl = (lane >> 4) * 4;
#pragma unroll
                for (int reg = 0; reg < 4; ++reg) {
                    sv1[half][sl + reg] = v1a[reg]; si1[half][sl + reg] = i1a[reg];
                    sv2[half][sl + reg] = v2a[reg]; si2[half][sl + reg] = i2a[reg];
                }
            }
            __syncthreads();
            if ((w & 1) == 0 && (lane & 15) == 0) {
                int half = w >> 1;
#pragma unroll
                for (int reg = 0; reg < 4; ++reg) {
                    int sl = (lane >> 4) * 4 + reg;
                    float v1 = v1a[reg], v2 = v2a[reg]; int i1 = i1a[reg], i2 = i2a[reg];
                    merge2(v1, i1, v2, i2, sv1[half][sl], si1[half][sl],
                           sv2[half][sl], si2[half][sl]);
                    int row = wr + fi * 16 + sl;
                    float gv1 = rv1[row], gv2 = rv2[row]; int gi1 = ri1[row], gi2 = ri2[row];
                    merge2(gv1, gi1, gv2, gi2, v1, i1, v2, i2);
                    rv1[row] = gv1; rv2[row] = gv2; ri1[row] = gi1; ri2[row] = gi2;
                }
            }
        }
    }
    __syncthreads();
    if (tid < 128) {
        float4 e;
        e.x = rv1[tid]; e.y = __int_as_float(ri1[tid]);
        e.z = rv2[tid]; e.w = __int_as_float(ri2[tid]);
        top2ws[(size_t)colgrp * M_ + rowblk + tid] = e;
    }
}

// ------------------------ finalize: merge 8 top-2 entries, exact fp32 recheck
__global__ __launch_bounds__(256) void k_finalize(const float4* __restrict__ top2ws,
                                                  const float* __restrict__ h,
                                                  const float* __restrict__ cb,
                                                  int* __restrict__ out) {
    const int w    = threadIdx.x >> 6;
    const int lane = threadIdx.x & 63;
    const int row  = blockIdx.x * 4 + w;

    int i1 = 0, i2 = 0;
    if (lane == 0) {
        float v1 = FLT_MAX, v2 = FLT_MAX; i1 = 0x7fffffff; i2 = 0x7fffffff;
#pragma unroll
        for (int e = 0; e < 8; ++e) {
            float4 t = top2ws[(size_t)e * M_ + row];
            merge2(v1, i1, v2, i2, t.x, __float_as_int(t.y), t.z, __float_as_int(t.w));
        }
    }
    i1 = __shfl(i1, 0, 64);
    i2 = __shfl(i2, 0, 64);

    float4 hv = *reinterpret_cast<const float4*>(&h[(size_t)row * CDIM + lane * 4]);
    float4 a  = *reinterpret_cast<const float4*>(&cb[(size_t)i1 * CDIM + lane * 4]);
    float4 b  = *reinterpret_cast<const float4*>(&cb[(size_t)i2 * CDIM + lane * 4]);
    float d1 = 0.f, d2 = 0.f, t;
    t = hv.x - a.x; d1 = fmaf(t, t, d1);  t = hv.y - a.y; d1 = fmaf(t, t, d1);
    t = hv.z - a.z; d1 = fmaf(t, t, d1);  t = hv.w - a.w; d1 = fmaf(t, t, d1);
    t = hv.x - b.x; d2 = fmaf(t, t, d2);  t = hv.y - b.y; d2 = fmaf(t, t, d2);
    t = hv.z - b.z; d2 = fmaf(t, t, d2);  t = hv.w - b.w; d2 = fmaf(t, t, d2);
#pragma unroll
    for (int m = 1; m < 64; m <<= 1) {
        d1 += __shfl_xor(d1, m, 64);
        d2 += __shfl_xor(d2, m, 64);
    }
    if (lane == 0)
        out[row] = (d2 < d1 || (d2 == d1 && i2 < i1)) ? i2 : i1;
}

extern "C" void kernel_launch(void* const* d_in, const int* in_sizes, int n_in,
                              void* d_out, int out_size, void* d_ws, size_t ws_size,
                              hipStream_t stream) {
    const float* x  = (const float*)d_in[0];
    const float* W  = (const float*)d_in[1];
    const float* cb = (const float*)d_in[2];

    char* base = (char*)d_ws;
    float*          h     = (float*)(base);                        // 16 MB
    float*          csq   = (float*)(base + 16777216);             // 32 KB
    unsigned short* Aexp  = (unsigned short*)(base + 16809984);    // 16 MB
    unsigned short* Bexp  = (unsigned short*)(base + 33587200);    // 8 MB
    float4*         top2  = (float4*)(base + 41975808);            // 2 MB
    int* out = (int*)d_out;

    k_csq      <<<dim3(K_ / 4),    dim3(256), 0, stream>>>(cb, csq);
    k_proj_ln  <<<dim3(M_ / 32),   dim3(256), 0, stream>>>(x, W, h, Aexp);
    k_expand_cb<<<dim3(K_ * 32 / 256), dim3(256), 0, stream>>>(cb, Bexp);
    k_dist_mfma<<<dim3(M_ / 128, 8), dim3(256), 0, stream>>>(Aexp, Bexp, csq, top2);
    k_finalize <<<dim3(M_ / 4),    dim3(256), 0, stream>>>(top2, h, cb, out);
}

// Round 5
// 459.607 us; speedup vs baseline: 3.1374x; 1.8792x over previous
//
#include <hip/hip_runtime.h>
#include <cfloat>

#define LN_EPS 1e-5f

constexpr int DIM  = 1024;
constexpr int CDIM = 256;
constexpr int K_   = 8192;
constexpr int M_   = 16384;

typedef short bf16x8 __attribute__((ext_vector_type(8)));
typedef float f32x4  __attribute__((ext_vector_type(4)));

__device__ inline unsigned short f2bf(float x) {          // RNE bf16
    unsigned u = __float_as_uint(x);
    unsigned r = (u + 0x7fffu + ((u >> 16) & 1u)) >> 16;
    return (unsigned short)r;
}
__device__ inline float bf2f(unsigned short b) {
    return __uint_as_float(((unsigned)b) << 16);
}

// merge top-2 list (v1,i1,v2,i2) with (ov1,oi1,ov2,oi2); order: (v,i) lexicographic
__device__ inline void merge2(float& v1, int& i1, float& v2, int& i2,
                              float ov1, int oi1, float ov2, int oi2) {
    bool oless = (ov1 < v1) || (ov1 == v1 && oi1 < i1);
    if (oless) {
        bool t = (v1 < ov2) || (v1 == ov2 && i1 < oi2);
        v2 = t ? v1 : ov2; i2 = t ? i1 : oi2;
        v1 = ov1; i1 = oi1;
    } else {
        bool t = (ov1 < v2) || (ov1 == v2 && oi1 < i2);
        v2 = t ? ov1 : v2; i2 = t ? oi1 : i2;
    }
}

// ---------------------------------------------------------------- c_sq
__global__ __launch_bounds__(256) void k_csq(const float* __restrict__ cb,
                                             float* __restrict__ csq) {
    int w    = threadIdx.x >> 6;
    int lane = threadIdx.x & 63;
    int row  = blockIdx.x * 4 + w;
    float4 v = *reinterpret_cast<const float4*>(&cb[(size_t)row * CDIM + lane * 4]);
    float s = v.x * v.x + v.y * v.y + v.z * v.z + v.w * v.w;
#pragma unroll
    for (int m = 1; m < 64; m <<= 1) s += __shfl_xor(s, m, 64);
    if (lane == 0) csq[row] = s;
}

// ------------------------- projection GEMM + fused LN + bf16 hi/lo split out
__global__ __launch_bounds__(256) void k_proj_ln(const float* __restrict__ x,
                                                 const float* __restrict__ W,
                                                 float* __restrict__ h,
                                                 unsigned short* __restrict__ Aexp) {
    __shared__ float xs[32][17];
    __shared__ float wsh[16][256];
    const int tid = threadIdx.x;
    const int tr  = tid >> 5;
    const int tc  = tid & 31;
    const int rowblk = blockIdx.x * 32;

    float acc[4][8];
#pragma unroll
    for (int i = 0; i < 4; i++)
#pragma unroll
        for (int j = 0; j < 8; j++) acc[i][j] = 0.f;

    for (int kc = 0; kc < DIM; kc += 16) {
        __syncthreads();
        if (tid < 128) {
            int row  = tid >> 2;
            int koff = (tid & 3) * 4;
            float4 v = *reinterpret_cast<const float4*>(
                &x[(size_t)(rowblk + row) * DIM + kc + koff]);
            xs[row][koff + 0] = v.x; xs[row][koff + 1] = v.y;
            xs[row][koff + 2] = v.z; xs[row][koff + 3] = v.w;
        }
        {
            int c0   = tid >> 2;
            int koff = (tid & 3) * 4;
#pragma unroll
            for (int p = 0; p < 4; ++p) {
                int c = c0 + 64 * p;
                float4 v = *reinterpret_cast<const float4*>(
                    &W[(size_t)c * DIM + kc + koff]);
                wsh[koff + 0][c] = v.x; wsh[koff + 1][c] = v.y;
                wsh[koff + 2][c] = v.z; wsh[koff + 3][c] = v.w;
            }
        }
        __syncthreads();
#pragma unroll
        for (int kk = 0; kk < 16; ++kk) {
            float xv[4];
#pragma unroll
            for (int i = 0; i < 4; i++) xv[i] = xs[tr * 4 + i][kk];
            float4 w0 = *reinterpret_cast<const float4*>(&wsh[kk][tc * 8]);
            float4 w1 = *reinterpret_cast<const float4*>(&wsh[kk][tc * 8 + 4]);
            float wv[8] = {w0.x, w0.y, w0.z, w0.w, w1.x, w1.y, w1.z, w1.w};
#pragma unroll
            for (int i = 0; i < 4; i++)
#pragma unroll
                for (int j = 0; j < 8; j++)
                    acc[i][j] = fmaf(xv[i], wv[j], acc[i][j]);
        }
    }

#pragma unroll
    for (int i = 0; i < 4; i++) {
        float s = 0.f;
#pragma unroll
        for (int j = 0; j < 8; j++) s += acc[i][j];
#pragma unroll
        for (int m = 1; m < 32; m <<= 1) s += __shfl_xor(s, m, 64);
        float mu = s * (1.0f / 256.0f);
        float sq = 0.f;
#pragma unroll
        for (int j = 0; j < 8; j++) { float d = acc[i][j] - mu; sq = fmaf(d, d, sq); }
#pragma unroll
        for (int m = 1; m < 32; m <<= 1) sq += __shfl_xor(sq, m, 64);
        float var   = sq * (1.0f / 256.0f);
        float scale = 1.0f / sqrtf(var + LN_EPS);
        int row = rowblk + tr * 4 + i;
        float o[8];
#pragma unroll
        for (int j = 0; j < 8; j++) o[j] = (acc[i][j] - mu) * scale;
        float4* dst = reinterpret_cast<float4*>(&h[(size_t)row * CDIM + tc * 8]);
        dst[0] = make_float4(o[0], o[1], o[2], o[3]);
        dst[1] = make_float4(o[4], o[5], o[6], o[7]);
        // bf16 hi/lo split, row layout: [hi(256) | lo(256)]
        bf16x8 hi8, lo8;
#pragma unroll
        for (int j = 0; j < 8; j++) {
            unsigned short hu = f2bf(o[j]);
            hi8[j] = (short)hu;
            lo8[j] = (short)f2bf(o[j] - bf2f(hu));
        }
        *reinterpret_cast<bf16x8*>(&Aexp[(size_t)row * 512 + tc * 8])       = hi8;
        *reinterpret_cast<bf16x8*>(&Aexp[(size_t)row * 512 + 256 + tc * 8]) = lo8;
    }
}

// ------------------------------------------- codebook bf16 hi/lo split
__global__ __launch_bounds__(256) void k_expand_cb(const float* __restrict__ cb,
                                                   unsigned short* __restrict__ Bexp) {
    int gid = blockIdx.x * 256 + threadIdx.x;  // 8192*32 threads
    int row = gid >> 5, t = gid & 31;
    const float4* src = reinterpret_cast<const float4*>(&cb[(size_t)row * CDIM + t * 8]);
    float4 v0 = src[0], v1 = src[1];
    float f[8] = {v0.x, v0.y, v0.z, v0.w, v1.x, v1.y, v1.z, v1.w};
    bf16x8 hi8, lo8;
#pragma unroll
    for (int j = 0; j < 8; j++) {
        unsigned short hu = f2bf(f[j]);
        hi8[j] = (short)hu;
        lo8[j] = (short)f2bf(f[j] - bf2f(hu));
    }
    *reinterpret_cast<bf16x8*>(&Bexp[(size_t)row * 512 + t * 8])       = hi8;
    *reinterpret_cast<bf16x8*>(&Bexp[(size_t)row * 512 + 256 + t * 8]) = lo8;
}

// --------------------------------------- bf16-split dist GEMM, quarter-staged
// 128 rows x 128 codes per subtile, 8 subtiles/block. Per k-quarter (64 k):
// stage Ahi/Alo/Bhi/Blo (64KB) once, run all 3 split-combos = 96 MFMA per
// barrier-pair. Thread-local top-1 (tagged), one butterfly merge at the end.
__global__ __launch_bounds__(256) void k_dist_mfma(const unsigned short* __restrict__ Aexp,
                                                   const unsigned short* __restrict__ Bexp,
                                                   const float* __restrict__ csq,
                                                   float4* __restrict__ top2ws) {
    __shared__ unsigned short AhiS[128 * 64];   // 16 KB each, row stride 128 B
    __shared__ unsigned short AloS[128 * 64];
    __shared__ unsigned short BhiS[128 * 64];
    __shared__ unsigned short BloS[128 * 64];
    __shared__ float sv1[4][64], sv2[4][64];
    __shared__ int   si1[4][64], si2[4][64];

    const int tid  = threadIdx.x;
    const int w    = tid >> 6;
    const int lane = tid & 63;
    const int rowblk = blockIdx.x * 128;
    const int colgrp = blockIdx.y;              // codes colgrp*1024 ...
    const int wr = (w >> 1) * 64;
    const int wc = (w & 1) * 64;

    const int srow  = lane >> 3;                // 0..7 within 8-row group
    const int gslot = (lane & 7) ^ srow;        // pre-swizzled global 16B slot

    const char* aBase = (const char*)Aexp +
        (size_t)(rowblk + w * 32 + srow) * 1024 + gslot * 16;

    int rA[4], rB[4], so[2];
#pragma unroll
    for (int f = 0; f < 4; ++f) {
        rA[f] = (wr + f * 16 + (lane & 15)) * 128;
        rB[f] = (wc + f * 16 + (lane & 15)) * 128;
    }
#pragma unroll
    for (int ks = 0; ks < 2; ++ks)
        so[ks] = ((ks * 4 + (lane >> 4)) ^ (lane & 7)) * 16;

    float bestv[16]; int bestt[16];
#pragma unroll
    for (int i = 0; i < 16; ++i) { bestv[i] = FLT_MAX; bestt[i] = 0; }

    for (int cs = 0; cs < 8; ++cs) {
        const int cbase = colgrp * 1024 + cs * 128;
        const char* bBase = (const char*)Bexp +
            (size_t)(cbase + w * 32 + srow) * 1024 + gslot * 16;
        float c4[4];
#pragma unroll
        for (int fj = 0; fj < 4; ++fj)
            c4[fj] = csq[cbase + wc + fj * 16 + (lane & 15)];

        f32x4 acc[4][4];
#pragma unroll
        for (int i = 0; i < 4; ++i)
#pragma unroll
            for (int j = 0; j < 4; ++j) acc[i][j] = (f32x4){0.f, 0.f, 0.f, 0.f};

        for (int q = 0; q < 4; ++q) {
            __syncthreads();
#pragma unroll
            for (int sub = 0; sub < 4; ++sub) {
                const int goff = sub * 8192 + q * 128;     // 8 rows x 1024B per sub
                const int loff = (w * 32 + sub * 8) * 64;  // shorts
                __builtin_amdgcn_global_load_lds(
                    (const __attribute__((address_space(1))) unsigned int*)(aBase + goff),
                    (__attribute__((address_space(3))) unsigned int*)(AhiS + loff), 16, 0, 0);
                __builtin_amdgcn_global_load_lds(
                    (const __attribute__((address_space(1))) unsigned int*)(aBase + goff + 512),
                    (__attribute__((address_space(3))) unsigned int*)(AloS + loff), 16, 0, 0);
                __builtin_amdgcn_global_load_lds(
                    (const __attribute__((address_space(1))) unsigned int*)(bBase + goff),
                    (__attribute__((address_space(3))) unsigned int*)(BhiS + loff), 16, 0, 0);
                __builtin_amdgcn_global_load_lds(
                    (const __attribute__((address_space(1))) unsigned int*)(bBase + goff + 512),
                    (__attribute__((address_space(3))) unsigned int*)(BloS + loff), 16, 0, 0);
            }
            __syncthreads();
#pragma unroll
            for (int ks = 0; ks < 2; ++ks) {
                bf16x8 ah[4], bh[4], bl[4], al[4];
#pragma unroll
                for (int f = 0; f < 4; ++f) {
                    ah[f] = *reinterpret_cast<const bf16x8*>((const char*)AhiS + rA[f] + so[ks]);
                    bh[f] = *reinterpret_cast<const bf16x8*>((const char*)BhiS + rB[f] + so[ks]);
                }
#pragma unroll
                for (int fi = 0; fi < 4; ++fi)
#pragma unroll
                    for (int fj = 0; fj < 4; ++fj)
                        acc[fi][fj] = __builtin_amdgcn_mfma_f32_16x16x32_bf16(
                            ah[fi], bh[fj], acc[fi][fj], 0, 0, 0);
#pragma unroll
                for (int f = 0; f < 4; ++f)
                    bl[f] = *reinterpret_cast<const bf16x8*>((const char*)BloS + rB[f] + so[ks]);
#pragma unroll
                for (int fi = 0; fi < 4; ++fi)
#pragma unroll
                    for (int fj = 0; fj < 4; ++fj)
                        acc[fi][fj] = __builtin_amdgcn_mfma_f32_16x16x32_bf16(
                            ah[fi], bl[fj], acc[fi][fj], 0, 0, 0);
#pragma unroll
                for (int f = 0; f < 4; ++f)
                    al[f] = *reinterpret_cast<const bf16x8*>((const char*)AloS + rA[f] + so[ks]);
#pragma unroll
                for (int fi = 0; fi < 4; ++fi)
#pragma unroll
                    for (int fj = 0; fj < 4; ++fj)
                        acc[fi][fj] = __builtin_amdgcn_mfma_f32_16x16x32_bf16(
                            al[fi], bh[fj], acc[fi][fj], 0, 0, 0);
            }
        }

        // thread-local top-1 update: dist = csq - 2*dot, scan order = ascending col
#pragma unroll
        for (int fi = 0; fi < 4; ++fi)
#pragma unroll
            for (int reg = 0; reg < 4; ++reg) {
                const int idx = fi * 4 + reg;
#pragma unroll
                for (int fj = 0; fj < 4; ++fj) {
                    float s = fmaf(-2.0f, acc[fi][fj][reg], c4[fj]);
                    bool c = s < bestv[idx];
                    bestv[idx] = c ? s : bestv[idx];
                    bestt[idx] = c ? (cs * 4 + fj) : bestt[idx];
                }
            }
    }

    // final: per (fi,reg) row, top-2 of the 16 lanes' top-1s via butterfly
#pragma unroll
    for (int fi = 0; fi < 4; ++fi)
#pragma unroll
        for (int reg = 0; reg < 4; ++reg) {
            const int idx = fi * 4 + reg;
            int   t  = bestt[idx];
            float v1 = bestv[idx];
            int   i1 = colgrp * 1024 + (t >> 2) * 128 + wc + (t & 3) * 16 + (lane & 15);
            float v2 = FLT_MAX; int i2 = 0x7fffffff;
#pragma unroll
            for (int m = 1; m < 16; m <<= 1) {
                float ov1 = __shfl_xor(v1, m, 64), ov2 = __shfl_xor(v2, m, 64);
                int   oi1 = __shfl_xor(i1, m, 64), oi2 = __shfl_xor(i2, m, 64);
                merge2(v1, i1, v2, i2, ov1, oi1, ov2, oi2);
            }
            if ((lane & 15) == 0) {
                int rloc = fi * 16 + (lane >> 4) * 4 + reg;   // row - wr
                sv1[w][rloc] = v1; sv2[w][rloc] = v2;
                si1[w][rloc] = i1; si2[w][rloc] = i2;
            }
        }
    __syncthreads();
    if (tid < 128) {
        int half = tid >> 6, local = tid & 63;
        int wA = half * 2, wB = half * 2 + 1;
        float v1 = sv1[wA][local], v2 = sv2[wA][local];
        int   i1 = si1[wA][local], i2 = si2[wA][local];
        merge2(v1, i1, v2, i2, sv1[wB][local], si1[wB][local],
               sv2[wB][local], si2[wB][local]);
        float4 e;
        e.x = v1; e.y = __int_as_float(i1);
        e.z = v2; e.w = __int_as_float(i2);
        top2ws[(size_t)colgrp * M_ + rowblk + tid] = e;
    }
}

// ------------------------ finalize: merge 8 top-2 entries, exact fp32 recheck
__global__ __launch_bounds__(256) void k_finalize(const float4* __restrict__ top2ws,
                                                  const float* __restrict__ h,
                                                  const float* __restrict__ cb,
                                                  int* __restrict__ out) {
    const int w    = threadIdx.x >> 6;
    const int lane = threadIdx.x & 63;
    const int row  = blockIdx.x * 4 + w;

    int i1 = 0, i2 = 0;
    if (lane == 0) {
        float v1 = FLT_MAX, v2 = FLT_MAX; i1 = 0x7fffffff; i2 = 0x7fffffff;
#pragma unroll
        for (int e = 0; e < 8; ++e) {
            float4 t = top2ws[(size_t)e * M_ + row];
            merge2(v1, i1, v2, i2, t.x, __float_as_int(t.y), t.z, __float_as_int(t.w));
        }
    }
    i1 = __shfl(i1, 0, 64);
    i2 = __shfl(i2, 0, 64);

    float4 hv = *reinterpret_cast<const float4*>(&h[(size_t)row * CDIM + lane * 4]);
    float4 a  = *reinterpret_cast<const float4*>(&cb[(size_t)i1 * CDIM + lane * 4]);
    float4 b  = *reinterpret_cast<const float4*>(&cb[(size_t)i2 * CDIM + lane * 4]);
    float d1 = 0.f, d2 = 0.f, t;
    t = hv.x - a.x; d1 = fmaf(t, t, d1);  t = hv.y - a.y; d1 = fmaf(t, t, d1);
    t = hv.z - a.z; d1 = fmaf(t, t, d1);  t = hv.w - a.w; d1 = fmaf(t, t, d1);
    t = hv.x - b.x; d2 = fmaf(t, t, d2);  t = hv.y - b.y; d2 = fmaf(t, t, d2);
    t = hv.z - b.z; d2 = fmaf(t, t, d2);  t = hv.w - b.w; d2 = fmaf(t, t, d2);
#pragma unroll
    for (int m = 1; m < 64; m <<= 1) {
        d1 += __shfl_xor(d1, m, 64);
        d2 += __shfl_xor(d2, m, 64);
    }
    if (lane == 0)
        out[row] = (d2 < d1 || (d2 == d1 && i2 < i1)) ? i2 : i1;
}

extern "C" void kernel_launch(void* const* d_in, const int* in_sizes, int n_in,
                              void* d_out, int out_size, void* d_ws, size_t ws_size,
                              hipStream_t stream) {
    const float* x  = (const float*)d_in[0];
    const float* W  = (const float*)d_in[1];
    const float* cb = (const float*)d_in[2];

    char* base = (char*)d_ws;
    float*          h     = (float*)(base);                        // 16 MB
    float*          csq   = (float*)(base + 16777216);             // 32 KB
    unsigned short* Aexp  = (unsigned short*)(base + 16809984);    // 16 MB
    unsigned short* Bexp  = (unsigned short*)(base + 33587200);    // 8 MB
    float4*         top2  = (float4*)(base + 41975808);            // 2 MB
    int* out = (int*)d_out;

    k_csq      <<<dim3(K_ / 4),    dim3(256), 0, stream>>>(cb, csq);
    k_proj_ln  <<<dim3(M_ / 32),   dim3(256), 0, stream>>>(x, W, h, Aexp);
    k_expand_cb<<<dim3(K_ * 32 / 256), dim3(256), 0, stream>>>(cb, Bexp);
    k_dist_mfma<<<dim3(M_ / 128, 8), dim3(256), 0, stream>>>(Aexp, Bexp, csq, top2);
    k_finalize <<<dim3(M_ / 4),    dim3(256), 0, stream>>>(top2, h, cb, out);
}

// Round 7
// 349.224 us; speedup vs baseline: 4.1291x; 1.3161x over previous
//
#include <hip/hip_runtime.h>
#include <cfloat>

#define LN_EPS 1e-5f

constexpr int DIM  = 1024;
constexpr int CDIM = 256;
constexpr int K_   = 8192;
constexpr int M_   = 16384;

typedef short    bf16x8 __attribute__((ext_vector_type(8)));
typedef _Float16 f16x8  __attribute__((ext_vector_type(8)));
typedef float    f32x4  __attribute__((ext_vector_type(4)));

// scales keep f16 lo-parts out of denormal range (MFMA FTZ-safe)
#define XSCALE 16.0f
#define WSCALE 1024.0f
#define UNSCALE (1.0f / 16384.0f)

__device__ inline unsigned short f2bf(float x) {          // RNE bf16
    unsigned u = __float_as_uint(x);
    unsigned r = (u + 0x7fffu + ((u >> 16) & 1u)) >> 16;
    return (unsigned short)r;
}
__device__ inline float bf2f(unsigned short b) {
    return __uint_as_float(((unsigned)b) << 16);
}

// merge top-2 list (v1,i1,v2,i2) with (ov1,oi1,ov2,oi2); order: (v,i) lexicographic
__device__ inline void merge2(float& v1, int& i1, float& v2, int& i2,
                              float ov1, int oi1, float ov2, int oi2) {
    bool oless = (ov1 < v1) || (ov1 == v1 && oi1 < i1);
    if (oless) {
        bool t = (v1 < ov2) || (v1 == ov2 && i1 < oi2);
        v2 = t ? v1 : ov2; i2 = t ? i1 : oi2;
        v1 = ov1; i1 = oi1;
    } else {
        bool t = (ov1 < v2) || (ov1 == v2 && oi1 < i2);
        v2 = t ? ov1 : v2; i2 = t ? oi1 : i2;
    }
}

// ---------------------------------------------------------------- c_sq
__global__ __launch_bounds__(256) void k_csq(const float* __restrict__ cb,
                                             float* __restrict__ csq) {
    int w    = threadIdx.x >> 6;
    int lane = threadIdx.x & 63;
    int row  = blockIdx.x * 4 + w;
    float4 v = *reinterpret_cast<const float4*>(&cb[(size_t)row * CDIM + lane * 4]);
    float s = v.x * v.x + v.y * v.y + v.z * v.z + v.w * v.w;
#pragma unroll
    for (int m = 1; m < 64; m <<= 1) s += __shfl_xor(s, m, 64);
    if (lane == 0) csq[row] = s;
}

// ----------------------------------- W f16 hi/lo split (scaled by WSCALE)
// Wexp row c: [hi(1024) | lo(1024)] f16, row stride 4096 B
__global__ __launch_bounds__(256) void k_expand_w(const float* __restrict__ W,
                                                  _Float16* __restrict__ Wexp) {
    int gid = blockIdx.x * 256 + threadIdx.x;   // 32768 threads
    int row = gid >> 7, j0 = (gid & 127) * 8;
    const float4* src = reinterpret_cast<const float4*>(&W[(size_t)row * DIM + j0]);
    float4 v0 = src[0], v1 = src[1];
    float f[8] = {v0.x, v0.y, v0.z, v0.w, v1.x, v1.y, v1.z, v1.w};
    f16x8 hi8, lo8;
#pragma unroll
    for (int j = 0; j < 8; j++) {
        float s = f[j] * WSCALE;
        _Float16 hv = (_Float16)s;
        hi8[j] = hv;
        lo8[j] = (_Float16)(s - (float)hv);
    }
    *reinterpret_cast<f16x8*>(&Wexp[(size_t)row * 2048 + j0])        = hi8;
    *reinterpret_cast<f16x8*>(&Wexp[(size_t)row * 2048 + 1024 + j0]) = lo8;
}

// ------------------- projection via f16 double-split MFMA + fused LN
// block: 512 thr (8 waves), 64 rows x 256 cols, K in 16 chunks of 64.
// wave w: rows (w>>2)*32.., cols (w&3)*64..  (2x4 fragments, acc 32 VGPR)
__global__ __launch_bounds__(512) void k_proj_mfma(const float* __restrict__ x,
                                                   const _Float16* __restrict__ Wexp,
                                                   float* __restrict__ h,
                                                   unsigned short* __restrict__ Aexp) {
    __shared__ _Float16 XhiS[64 * 64];    // 8 KB, row stride 128 B
    __shared__ _Float16 XloS[64 * 64];
    __shared__ _Float16 WhiS[256 * 64];   // 32 KB
    __shared__ _Float16 WloS[256 * 64];
    __shared__ float psum[4][64], psq[4][64];

    const int tid  = threadIdx.x;
    const int w    = tid >> 6;            // 0..7
    const int lane = tid & 63;
    const int rowblk = blockIdx.x * 64;
    const int rw = (w >> 2) * 32;         // wave row base
    const int cw = (w & 3) * 64;          // wave col base

    const int srow  = lane >> 3;
    const int gslot = (lane & 7) ^ srow;  // pre-swizzled 16B slot (dist idiom)

    // W staging base: Wexp rows w*32+sub*8+srow, hi slice q*128 B, lo +2048
    const char* wBase = (const char*)Wexp + (size_t)(w * 32 + srow) * 4096 + gslot * 16;

    // X: thread t handles row tid>>3, 16B chunk tid&7 (one chunk per buffer)
    const int xrow   = tid >> 3;
    const int xchunk = tid & 7;
    const float* xsrc = &x[(size_t)(rowblk + xrow) * DIM + xchunk * 8];
    _Float16* xhidst = XhiS + xrow * 64 + (xchunk ^ (xrow & 7)) * 8;
    _Float16* xlodst = XloS + xrow * 64 + (xchunk ^ (xrow & 7)) * 8;

    int rX[2], rW[4], so[2];
#pragma unroll
    for (int f = 0; f < 2; ++f) rX[f] = (rw + f * 16 + (lane & 15)) * 128;
#pragma unroll
    for (int f = 0; f < 4; ++f) rW[f] = (cw + f * 16 + (lane & 15)) * 128;
#pragma unroll
    for (int ks = 0; ks < 2; ++ks)
        so[ks] = ((ks * 4 + (lane >> 4)) ^ (lane & 7)) * 16;

    f32x4 acc[2][4];
#pragma unroll
    for (int i = 0; i < 2; ++i)
#pragma unroll
        for (int j = 0; j < 4; ++j) acc[i][j] = (f32x4){0.f, 0.f, 0.f, 0.f};

    float4 nx0 = *reinterpret_cast<const float4*>(xsrc);
    float4 nx1 = *reinterpret_cast<const float4*>(xsrc + 4);

    for (int q = 0; q < 16; ++q) {
        float4 cx0 = nx0, cx1 = nx1;
        if (q < 15) {                                   // prefetch next chunk
            nx0 = *reinterpret_cast<const float4*>(xsrc + (q + 1) * 64);
            nx1 = *reinterpret_cast<const float4*>(xsrc + (q + 1) * 64 + 4);
        }
        __syncthreads();
        // W: global_load_lds staging (hi+lo), 8 gloads per wave
#pragma unroll
        for (int sub = 0; sub < 4; ++sub) {
            const char* wg = wBase + (size_t)sub * 8 * 4096 + q * 128;
            _Float16* dhi = WhiS + (w * 32 + sub * 8) * 64;
            _Float16* dlo = WloS + (w * 32 + sub * 8) * 64;
            __builtin_amdgcn_global_load_lds(
                (const __attribute__((address_space(1))) unsigned int*)wg,
                (__attribute__((address_space(3))) unsigned int*)dhi, 16, 0, 0);
            __builtin_amdgcn_global_load_lds(
                (const __attribute__((address_space(1))) unsigned int*)(wg + 2048),
                (__attribute__((address_space(3))) unsigned int*)dlo, 16, 0, 0);
        }
        // X: convert (scaled) + swizzled ds_write
        {
            float xv[8] = {cx0.x, cx0.y, cx0.z, cx0.w, cx1.x, cx1.y, cx1.z, cx1.w};
            f16x8 hi8, lo8;
#pragma unroll
            for (int j = 0; j < 8; ++j) {
                float s = xv[j] * XSCALE;
                _Float16 hv = (_Float16)s;
                hi8[j] = hv;
                lo8[j] = (_Float16)(s - (float)hv);
            }
            *reinterpret_cast<f16x8*>(xhidst) = hi8;
            *reinterpret_cast<f16x8*>(xlodst) = lo8;
        }
        __syncthreads();
#pragma unroll
        for (int ks = 0; ks < 2; ++ks) {
            f16x8 ah[2], al[2], bh[4], bl[4];
#pragma unroll
            for (int f = 0; f < 2; ++f)
                ah[f] = *reinterpret_cast<const f16x8*>((const char*)XhiS + rX[f] + so[ks]);
#pragma unroll
            for (int f = 0; f < 4; ++f)
                bh[f] = *reinterpret_cast<const f16x8*>((const char*)WhiS + rW[f] + so[ks]);
#pragma unroll
            for (int fi = 0; fi < 2; ++fi)
#pragma unroll
                for (int fj = 0; fj < 4; ++fj)
                    acc[fi][fj] = __builtin_amdgcn_mfma_f32_16x16x32_f16(
                        ah[fi], bh[fj], acc[fi][fj], 0, 0, 0);
#pragma unroll
            for (int f = 0; f < 4; ++f)
                bl[f] = *reinterpret_cast<const f16x8*>((const char*)WloS + rW[f] + so[ks]);
#pragma unroll
            for (int fi = 0; fi < 2; ++fi)
#pragma unroll
                for (int fj = 0; fj < 4; ++fj)
                    acc[fi][fj] = __builtin_amdgcn_mfma_f32_16x16x32_f16(
                        ah[fi], bl[fj], acc[fi][fj], 0, 0, 0);
#pragma unroll
            for (int f = 0; f < 2; ++f)
                al[f] = *reinterpret_cast<const f16x8*>((const char*)XloS + rX[f] + so[ks]);
#pragma unroll
            for (int fi = 0; fi < 2; ++fi)
#pragma unroll
                for (int fj = 0; fj < 4; ++fj)
                    acc[fi][fj] = __builtin_amdgcn_mfma_f32_16x16x32_f16(
                        al[fi], bh[fj], acc[fi][fj], 0, 0, 0);
        }
    }

    // ---- fused LayerNorm: cross-wave partials (sum, sumsq) per row
#pragma unroll
    for (int fi = 0; fi < 2; ++fi)
#pragma unroll
        for (int reg = 0; reg < 4; ++reg) {
            float s = 0.f, ss = 0.f;
#pragma unroll
            for (int fj = 0; fj < 4; ++fj) {
                float v = acc[fi][fj][reg] * UNSCALE;
                s += v; ss = fmaf(v, v, ss);
            }
#pragma unroll
            for (int m = 1; m < 16; m <<= 1) {
                s  += __shfl_xor(s, m, 64);
                ss += __shfl_xor(ss, m, 64);
            }
            if ((lane & 15) == 0) {
                int row = rw + fi * 16 + (lane >> 4) * 4 + reg;
                psum[w & 3][row] = s;
                psq[w & 3][row]  = ss;
            }
        }
    __syncthreads();
#pragma unroll
    for (int fi = 0; fi < 2; ++fi)
#pragma unroll
        for (int reg = 0; reg < 4; ++reg) {
            int row = rw + fi * 16 + (lane >> 4) * 4 + reg;
            float S = psum[0][row] + psum[1][row] + psum[2][row] + psum[3][row];
            float Q = psq[0][row]  + psq[1][row]  + psq[2][row]  + psq[3][row];
            float mu  = S * (1.0f / 256.0f);
            float var = Q * (1.0f / 256.0f) - mu * mu;
            float rstd = 1.0f / sqrtf(var + LN_EPS);
            int row_g = rowblk + row;
#pragma unroll
            for (int fj = 0; fj < 4; ++fj) {
                int col = cw + fj * 16 + (lane & 15);
                float v = (acc[fi][fj][reg] * UNSCALE - mu) * rstd;
                h[(size_t)row_g * CDIM + col] = v;
                unsigned short hu = f2bf(v);
                Aexp[(size_t)row_g * 512 + col]       = hu;
                Aexp[(size_t)row_g * 512 + 256 + col] = f2bf(v - bf2f(hu));
            }
        }
}

// ------------------------------------------- codebook bf16 hi/lo split
__global__ __launch_bounds__(256) void k_expand_cb(const float* __restrict__ cb,
                                                   unsigned short* __restrict__ Bexp) {
    int gid = blockIdx.x * 256 + threadIdx.x;  // 8192*32 threads
    int row = gid >> 5, t = gid & 31;
    const float4* src = reinterpret_cast<const float4*>(&cb[(size_t)row * CDIM + t * 8]);
    float4 v0 = src[0], v1 = src[1];
    float f[8] = {v0.x, v0.y, v0.z, v0.w, v1.x, v1.y, v1.z, v1.w};
    bf16x8 hi8, lo8;
#pragma unroll
    for (int j = 0; j < 8; j++) {
        unsigned short hu = f2bf(f[j]);
        hi8[j] = (short)hu;
        lo8[j] = (short)f2bf(f[j] - bf2f(hu));
    }
    *reinterpret_cast<bf16x8*>(&Bexp[(size_t)row * 512 + t * 8])       = hi8;
    *reinterpret_cast<bf16x8*>(&Bexp[(size_t)row * 512 + 256 + t * 8]) = lo8;
}

// --------------------------------------- bf16-split dist GEMM, quarter-staged
__global__ __launch_bounds__(256) void k_dist_mfma(const unsigned short* __restrict__ Aexp,
                                                   const unsigned short* __restrict__ Bexp,
                                                   const float* __restrict__ csq,
                                                   float4* __restrict__ top2ws) {
    __shared__ unsigned short AhiS[128 * 64];   // 16 KB each, row stride 128 B
    __shared__ unsigned short AloS[128 * 64];
    __shared__ unsigned short BhiS[128 * 64];
    __shared__ unsigned short BloS[128 * 64];
    __shared__ float sv1[4][64], sv2[4][64];
    __shared__ int   si1[4][64], si2[4][64];

    const int tid  = threadIdx.x;
    const int w    = tid >> 6;
    const int lane = tid & 63;
    const int rowblk = blockIdx.x * 128;
    const int colgrp = blockIdx.y;              // codes colgrp*1024 ...
    const int wr = (w >> 1) * 64;
    const int wc = (w & 1) * 64;

    const int srow  = lane >> 3;
    const int gslot = (lane & 7) ^ srow;

    const char* aBase = (const char*)Aexp +
        (size_t)(rowblk + w * 32 + srow) * 1024 + gslot * 16;

    int rA[4], rB[4], so[2];
#pragma unroll
    for (int f = 0; f < 4; ++f) {
        rA[f] = (wr + f * 16 + (lane & 15)) * 128;
        rB[f] = (wc + f * 16 + (lane & 15)) * 128;
    }
#pragma unroll
    for (int ks = 0; ks < 2; ++ks)
        so[ks] = ((ks * 4 + (lane >> 4)) ^ (lane & 7)) * 16;

    float bestv[16]; int bestt[16];
#pragma unroll
    for (int i = 0; i < 16; ++i) { bestv[i] = FLT_MAX; bestt[i] = 0; }

    for (int cs = 0; cs < 8; ++cs) {
        const int cbase = colgrp * 1024 + cs * 128;
        const char* bBase = (const char*)Bexp +
            (size_t)(cbase + w * 32 + srow) * 1024 + gslot * 16;
        float c4[4];
#pragma unroll
        for (int fj = 0; fj < 4; ++fj)
            c4[fj] = csq[cbase + wc + fj * 16 + (lane & 15)];

        f32x4 acc[4][4];
#pragma unroll
        for (int i = 0; i < 4; ++i)
#pragma unroll
            for (int j = 0; j < 4; ++j) acc[i][j] = (f32x4){0.f, 0.f, 0.f, 0.f};

        for (int q = 0; q < 4; ++q) {
            __syncthreads();
#pragma unroll
            for (int sub = 0; sub < 4; ++sub) {
                const int goff = sub * 8192 + q * 128;
                const int loff = (w * 32 + sub * 8) * 64;
                __builtin_amdgcn_global_load_lds(
                    (const __attribute__((address_space(1))) unsigned int*)(aBase + goff),
                    (__attribute__((address_space(3))) unsigned int*)(AhiS + loff), 16, 0, 0);
                __builtin_amdgcn_global_load_lds(
                    (const __attribute__((address_space(1))) unsigned int*)(aBase + goff + 512),
                    (__attribute__((address_space(3))) unsigned int*)(AloS + loff), 16, 0, 0);
                __builtin_amdgcn_global_load_lds(
                    (const __attribute__((address_space(1))) unsigned int*)(bBase + goff),
                    (__attribute__((address_space(3))) unsigned int*)(BhiS + loff), 16, 0, 0);
                __builtin_amdgcn_global_load_lds(
                    (const __attribute__((address_space(1))) unsigned int*)(bBase + goff + 512),
                    (__attribute__((address_space(3))) unsigned int*)(BloS + loff), 16, 0, 0);
            }
            __syncthreads();
#pragma unroll
            for (int ks = 0; ks < 2; ++ks) {
                bf16x8 ah[4], bh[4], bl[4], al[4];
#pragma unroll
                for (int f = 0; f < 4; ++f) {
                    ah[f] = *reinterpret_cast<const bf16x8*>((const char*)AhiS + rA[f] + so[ks]);
                    bh[f] = *reinterpret_cast<const bf16x8*>((const char*)BhiS + rB[f] + so[ks]);
                }
#pragma unroll
                for (int fi = 0; fi < 4; ++fi)
#pragma unroll
                    for (int fj = 0; fj < 4; ++fj)
                        acc[fi][fj] = __builtin_amdgcn_mfma_f32_16x16x32_bf16(
                            ah[fi], bh[fj], acc[fi][fj], 0, 0, 0);
#pragma unroll
                for (int f = 0; f < 4; ++f)
                    bl[f] = *reinterpret_cast<const bf16x8*>((const char*)BloS + rB[f] + so[ks]);
#pragma unroll
                for (int fi = 0; fi < 4; ++fi)
#pragma unroll
                    for (int fj = 0; fj < 4; ++fj)
                        acc[fi][fj] = __builtin_amdgcn_mfma_f32_16x16x32_bf16(
                            ah[fi], bl[fj], acc[fi][fj], 0, 0, 0);
#pragma unroll
                for (int f = 0; f < 4; ++f)
                    al[f] = *reinterpret_cast<const bf16x8*>((const char*)AloS + rA[f] + so[ks]);
#pragma unroll
                for (int fi = 0; fi < 4; ++fi)
#pragma unroll
                    for (int fj = 0; fj < 4; ++fj)
                        acc[fi][fj] = __builtin_amdgcn_mfma_f32_16x16x32_bf16(
                            al[fi], bh[fj], acc[fi][fj], 0, 0, 0);
            }
        }

#pragma unroll
        for (int fi = 0; fi < 4; ++fi)
#pragma unroll
            for (int reg = 0; reg < 4; ++reg) {
                const int idx = fi * 4 + reg;
#pragma unroll
                for (int fj = 0; fj < 4; ++fj) {
                    float s = fmaf(-2.0f, acc[fi][fj][reg], c4[fj]);
                    bool c = s < bestv[idx];
                    bestv[idx] = c ? s : bestv[idx];
                    bestt[idx] = c ? (cs * 4 + fj) : bestt[idx];
                }
            }
    }

#pragma unroll
    for (int fi = 0; fi < 4; ++fi)
#pragma unroll
        for (int reg = 0; reg < 4; ++reg) {
            const int idx = fi * 4 + reg;
            int   t  = bestt[idx];
            float v1 = bestv[idx];
            int   i1 = colgrp * 1024 + (t >> 2) * 128 + wc + (t & 3) * 16 + (lane & 15);
            float v2 = FLT_MAX; int i2 = 0x7fffffff;
#pragma unroll
            for (int m = 1; m < 16; m <<= 1) {
                float ov1 = __shfl_xor(v1, m, 64), ov2 = __shfl_xor(v2, m, 64);
                int   oi1 = __shfl_xor(i1, m, 64), oi2 = __shfl_xor(i2, m, 64);
                merge2(v1, i1, v2, i2, ov1, oi1, ov2, oi2);
            }
            if ((lane & 15) == 0) {
                int rloc = fi * 16 + (lane >> 4) * 4 + reg;
                sv1[w][rloc] = v1; sv2[w][rloc] = v2;
                si1[w][rloc] = i1; si2[w][rloc] = i2;
            }
        }
    __syncthreads();
    if (tid < 128) {
        int half = tid >> 6, local = tid & 63;
        int wA = half * 2, wB = half * 2 + 1;
        float v1 = sv1[wA][local], v2 = sv2[wA][local];
        int   i1 = si1[wA][local], i2 = si2[wA][local];
        merge2(v1, i1, v2, i2, sv1[wB][local], si1[wB][local],
               sv2[wB][local], si2[wB][local]);
        float4 e;
        e.x = v1; e.y = __int_as_float(i1);
        e.z = v2; e.w = __int_as_float(i2);
        top2ws[(size_t)colgrp * M_ + rowblk + tid] = e;
    }
}

// ------------------------ finalize: merge 8 top-2 entries, exact fp32 recheck
__global__ __launch_bounds__(256) void k_finalize(const float4* __restrict__ top2ws,
                                                  const float* __restrict__ h,
                                                  const float* __restrict__ cb,
                                                  int* __restrict__ out) {
    const int w    = threadIdx.x >> 6;
    const int lane = threadIdx.x & 63;
    const int row  = blockIdx.x * 4 + w;

    int i1 = 0, i2 = 0;
    if (lane == 0) {
        float v1 = FLT_MAX, v2 = FLT_MAX; i1 = 0x7fffffff; i2 = 0x7fffffff;
#pragma unroll
        for (int e = 0; e < 8; ++e) {
            float4 t = top2ws[(size_t)e * M_ + row];
            merge2(v1, i1, v2, i2, t.x, __float_as_int(t.y), t.z, __float_as_int(t.w));
        }
    }
    i1 = __shfl(i1, 0, 64);
    i2 = __shfl(i2, 0, 64);

    float4 hv = *reinterpret_cast<const float4*>(&h[(size_t)row * CDIM + lane * 4]);
    float4 a  = *reinterpret_cast<const float4*>(&cb[(size_t)i1 * CDIM + lane * 4]);
    float4 b  = *reinterpret_cast<const float4*>(&cb[(size_t)i2 * CDIM + lane * 4]);
    float d1 = 0.f, d2 = 0.f, t;
    t = hv.x - a.x; d1 = fmaf(t, t, d1);  t = hv.y - a.y; d1 = fmaf(t, t, d1);
    t = hv.z - a.z; d1 = fmaf(t, t, d1);  t = hv.w - a.w; d1 = fmaf(t, t, d1);
    t = hv.x - b.x; d2 = fmaf(t, t, d2);  t = hv.y - b.y; d2 = fmaf(t, t, d2);
    t = hv.z - b.z; d2 = fmaf(t, t, d2);  t = hv.w - b.w; d2 = fmaf(t, t, d2);
#pragma unroll
    for (int m = 1; m < 64; m <<= 1) {
        d1 += __shfl_xor(d1, m, 64);
        d2 += __shfl_xor(d2, m, 64);
    }
    if (lane == 0)
        out[row] = (d2 < d1 || (d2 == d1 && i2 < i1)) ? i2 : i1;
}

extern "C" void kernel_launch(void* const* d_in, const int* in_sizes, int n_in,
                              void* d_out, int out_size, void* d_ws, size_t ws_size,
                              hipStream_t stream) {
    const float* x  = (const float*)d_in[0];
    const float* W  = (const float*)d_in[1];
    const float* cb = (const float*)d_in[2];

    char* base = (char*)d_ws;
    float*          h     = (float*)(base);                        // 16 MB
    float*          csq   = (float*)(base + 16777216);             // 32 KB
    unsigned short* Aexp  = (unsigned short*)(base + 16809984);    // 16 MB
    unsigned short* Bexp  = (unsigned short*)(base + 33587200);    // 8 MB
    float4*         top2  = (float4*)(base + 41975808);            // 2 MB
    _Float16*       Wexp  = (_Float16*)(base + 44072960);          // 1 MB
    int* out = (int*)d_out;

    k_csq      <<<dim3(K_ / 4),        dim3(256), 0, stream>>>(cb, csq);
    k_expand_w <<<dim3(128),           dim3(256), 0, stream>>>(W, Wexp);
    k_expand_cb<<<dim3(K_ * 32 / 256), dim3(256), 0, stream>>>(cb, Bexp);
    k_proj_mfma<<<dim3(M_ / 64),       dim3(512), 0, stream>>>(x, Wexp, h, Aexp);
    k_dist_mfma<<<dim3(M_ / 128, 8),   dim3(256), 0, stream>>>(Aexp, Bexp, csq, top2);
    k_finalize <<<dim3(M_ / 4),        dim3(256), 0, stream>>>(top2, h, cb, out);
}